// Round 1
// baseline (2008.106 us; speedup 1.0000x reference)
//
#include <hip/hip_runtime.h>

// Fully fused quantized encoder. One kernel, zero workspace.
// Per block: 128 output frames, 1 warm-up pass (32 frames) + 4 real passes.
// LDS: Tb 32KB activation tile [c][frame], r2/ci3 int8 history rings.
// GEMV: thread = 4 oc x 8 frames (32 acc), W streamed from global (L1/L2).

#define CIN   256
#define LOUT  120000
#define TIN   600000
#define PF    32                         // frames per pass
#define FB    128                        // output frames per block
#define NBLK  ((LOUT + FB - 1) / FB)     // 938

__device__ __forceinline__ float lrelu(float v){ return v >= 0.0f ? v : 0.3f*v; }
__device__ __forceinline__ float clip8(float v){ return fminf(fmaxf(v, -128.0f), 127.0f); }

__device__ __forceinline__ void gemv(const float* __restrict__ W,
                                     const float* __restrict__ Tb,
                                     int oc4, int fb0, float acc[4][8])
{
#pragma unroll
  for (int a = 0; a < 4; ++a)
#pragma unroll
    for (int b = 0; b < 8; ++b) acc[a][b] = 0.0f;
  const float* wp = W + oc4;
#pragma unroll 4
  for (int ic = 0; ic < CIN; ++ic) {
    const float4 a0 = *(const float4*)(&Tb[ic*PF + fb0]);
    const float4 a1 = *(const float4*)(&Tb[ic*PF + fb0 + 4]);
    const float4 wv = *(const float4*)(&wp[ic*CIN]);
    const float av[8] = {a0.x,a0.y,a0.z,a0.w,a1.x,a1.y,a1.z,a1.w};
    const float wa[4] = {wv.x,wv.y,wv.z,wv.w};
#pragma unroll
    for (int a = 0; a < 4; ++a)
#pragma unroll
      for (int b = 0; b < 8; ++b)
        acc[a][b] = fmaf(wa[a], av[b], acc[a][b]);
  }
}

__launch_bounds__(256, 2)
__global__ void enc_kernel(const float* __restrict__ x,
                           const float* __restrict__ w_first, const float* __restrict__ b_first,
                           const float* __restrict__ w_dw1, const float* __restrict__ b_dw1,
                           const float* __restrict__ w_pw1, const float* __restrict__ b_pw1,
                           const float* __restrict__ w_lc1, const float* __restrict__ b_lc1,
                           const float* __restrict__ w_dw2, const float* __restrict__ b_dw2,
                           const float* __restrict__ w_pw2, const float* __restrict__ b_pw2,
                           const float* __restrict__ w_lc2, const float* __restrict__ b_lc2,
                           const float* __restrict__ w_dw3, const float* __restrict__ b_dw3,
                           const float* __restrict__ w_pw3, const float* __restrict__ b_pw3,
                           const float* __restrict__ w_lc3, const float* __restrict__ b_lc3,
                           float* __restrict__ out)
{
  __shared__ __align__(16) float       Tb[CIN * PF];   // [c][frame] 32 KB
  __shared__ __align__(16) signed char r2r[48 * CIN];  // r2 ring (int, exact) 12 KB
  __shared__ __align__(16) signed char c3r[56 * CIN];  // ci3 ring (int, exact) 14 KB

  const int tid = threadIdx.x;
  const int t0  = blockIdx.x * FB;
  const int oc4 = (tid & 63) * 4;   // 4 consecutive output channels
  const int fg  = tid >> 6;         // wave id 0..3
  const int fb0 = fg * 8;           // 8 frames per thread

  float acc[4][8];
  float resf[4][8];                 // holds r2 after stage3, r3 after stage6

  for (int pass = 0; pass < 5; ++pass) {
    const int pt0 = t0 - 32 + pass * 32;     // first frame of this pass
    __syncthreads();                          // Tb free (prev pass reads done)

    // ---------------- stage 1: first conv + leaky + dw1 -> Tb ----------------
    {
      const int c = tid;
      float wf[10];
#pragma unroll
      for (int k = 0; k < 10; ++k) wf[k] = w_first[k*CIN + c];
      const float bfv = b_first[c];
      const float d0 = w_dw1[c], d1 = w_dw1[CIN + c], d2 = w_dw1[2*CIN + c];
      const float bd = b_dw1[c];
      auto ci1 = [&](int t) -> float {
        if (t < 0) return 0.0f;               // res1_buffer zero pad
        float a = 0.0f;
        const int base = 5*t - 5;             // first_buffer zero pad via ix<0
#pragma unroll
        for (int k = 0; k < 10; ++k) {
          const int ix = base + k;
          const float xv = (ix >= 0 && ix < TIN) ? x[ix] : 0.0f;
          a = fmaf(xv, wf[k], a);
        }
        return lrelu(a + bfv);
      };
      float cm2 = ci1(pt0 - 2), cm1 = ci1(pt0 - 1);
      for (int j = 0; j < PF; ++j) {
        const float c0 = ci1(pt0 + j);
        Tb[c*PF + j] = fmaf(d0, cm2, fmaf(d1, cm1, fmaf(d2, c0, bd)));
        cm2 = cm1; cm1 = c0;
      }
    }
    __syncthreads();

    // ---------------- stage 2: pw1 GEMV -> quant -> leaky -> Tb --------------
    gemv(w_pw1, Tb, oc4, fb0, acc);
    {
      const float4 b4 = *(const float4*)&b_pw1[oc4];
      const float bb[4] = {b4.x, b4.y, b4.z, b4.w};
#pragma unroll
      for (int a = 0; a < 4; ++a)
#pragma unroll
        for (int b = 0; b < 8; ++b) {
          const float h = acc[a][b] + bb[a];
          const float q = clip8(rintf(h / 17.62967872619629f + 67.0f)); // quant s=17.63,o=-67
          acc[a][b] = lrelu(q);
        }
    }
    __syncthreads();
#pragma unroll
    for (int a = 0; a < 4; ++a) {
      *(float4*)&Tb[(oc4 + a)*PF + fb0]     = make_float4(acc[a][0],acc[a][1],acc[a][2],acc[a][3]);
      *(float4*)&Tb[(oc4 + a)*PF + fb0 + 4] = make_float4(acc[a][4],acc[a][5],acc[a][6],acc[a][7]);
    }
    __syncthreads();

    // ------- stage 3: lc1 GEMV -> dequant -> +r1 -> quant -> r2 (regs+ring) --
    gemv(w_lc1, Tb, oc4, fb0, acc);
    {
      const float4 b4 = *(const float4*)&b_lc1[oc4];
      const float bb[4] = {b4.x, b4.y, b4.z, b4.w};
      // recompute r1 = first conv (pre-leaky) for own (oc, frame) tile
      float r1v[4][8];
#pragma unroll
      for (int a = 0; a < 4; ++a)
#pragma unroll
        for (int b = 0; b < 8; ++b) r1v[a][b] = 0.0f;
#pragma unroll
      for (int k = 0; k < 10; ++k) {
        const float4 wk = *(const float4*)&w_first[k*CIN + oc4];
        const float wa[4] = {wk.x, wk.y, wk.z, wk.w};
#pragma unroll
        for (int b = 0; b < 8; ++b) {
          const int t = pt0 + fb0 + b;
          const int ix = 5*t - 5 + k;
          const float xv = (ix >= 0 && ix < TIN) ? x[ix] : 0.0f;
#pragma unroll
          for (int a = 0; a < 4; ++a) r1v[a][b] = fmaf(xv, wa[a], r1v[a][b]);
        }
      }
      const float4 bf4 = *(const float4*)&b_first[oc4];
      const float bfa[4] = {bf4.x, bf4.y, bf4.z, bf4.w};
#pragma unroll
      for (int a = 0; a < 4; ++a)
#pragma unroll
        for (int b = 0; b < 8; ++b) {
          const float ro1 = (acc[a][b] + bb[a] - 16.0f) * 6.528060436248779f; // dequant o=-16
          const float v = (r1v[a][b] + bfa[a]) + ro1;
          resf[a][b] = clip8(rintf(v / 12.716455459594727f + 23.0f));         // quant o=-23
        }
#pragma unroll
      for (int b = 0; b < 8; ++b) {
        const int t = pt0 + fb0 + b;
        const int slot = (t + 96) % 48;
        const int p = ((int)resf[0][b] & 255)
                    | (((int)resf[1][b] & 255) << 8)
                    | (((int)resf[2][b] & 255) << 16)
                    | (((int)resf[3][b] & 255) << 24);
        *(int*)&r2r[slot*CIN + oc4] = p;
      }
    }
    __syncthreads();

    // ---------------- stage 4: dw2 (dil 3) from r2 ring -> Tb ----------------
    {
      const int c = tid;
      const float d0 = w_dw2[c], d1 = w_dw2[CIN + c], d2 = w_dw2[2*CIN + c];
      const float bd = b_dw2[c];
      auto ci2 = [&](int t) -> float {
        if (t < 0) return -47.0f;             // quantize(0) with s=5.548,o=47
        const float r = (float)r2r[((t + 96) % 48)*CIN + c];
        const float dq = (lrelu(r) + 47.0f) * 5.548006534576416f;
        return clip8(rintf(dq / 5.548006534576416f - 47.0f));
      };
      for (int j = 0; j < PF; ++j) {
        const int t = pt0 + j;
        Tb[c*PF + j] = fmaf(d0, ci2(t-6), fmaf(d1, ci2(t-3), fmaf(d2, ci2(t), bd)));
      }
    }
    __syncthreads();

    // ---------------- stage 5: pw2 GEMV -> leaky -> Tb -----------------------
    gemv(w_pw2, Tb, oc4, fb0, acc);
    {
      const float4 b4 = *(const float4*)&b_pw2[oc4];
      const float bb[4] = {b4.x, b4.y, b4.z, b4.w};
#pragma unroll
      for (int a = 0; a < 4; ++a)
#pragma unroll
        for (int b = 0; b < 8; ++b) acc[a][b] = lrelu(acc[a][b] + bb[a]);
    }
    __syncthreads();
#pragma unroll
    for (int a = 0; a < 4; ++a) {
      *(float4*)&Tb[(oc4 + a)*PF + fb0]     = make_float4(acc[a][0],acc[a][1],acc[a][2],acc[a][3]);
      *(float4*)&Tb[(oc4 + a)*PF + fb0 + 4] = make_float4(acc[a][4],acc[a][5],acc[a][6],acc[a][7]);
    }
    __syncthreads();

    // ------- stage 6: lc2 GEMV -> r3 = ro2 + r2 (regs); ci3 -> ring ----------
    gemv(w_lc2, Tb, oc4, fb0, acc);
    {
      const float4 b4 = *(const float4*)&b_lc2[oc4];
      const float bb[4] = {b4.x, b4.y, b4.z, b4.w};
#pragma unroll
      for (int a = 0; a < 4; ++a)
#pragma unroll
        for (int b = 0; b < 8; ++b) {
          const float ro2 = acc[a][b] + bb[a];
          resf[a][b] = ro2 + resf[a][b];      // r3 = ro2 + r2
        }
#pragma unroll
      for (int b = 0; b < 8; ++b) {
        const int t = pt0 + fb0 + b;
        const int slot = (t + 112) % 56;
        int p = 0;
#pragma unroll
        for (int a = 0; a < 4; ++a) {
          const float dq = (lrelu(resf[a][b]) + 38.0f) * 4.458680152893066f;
          const float q  = clip8(rintf(dq / 4.458680152893066f - 38.0f));
          p |= ((int)q & 255) << (8*a);
        }
        *(int*)&c3r[slot*CIN + oc4] = p;
      }
    }
    __syncthreads();

    if (pass > 0) {
      // -------------- stage 7: dw3 (dil 9) from ci3 ring -> Tb ---------------
      {
        const int c = tid;
        const float d0 = w_dw3[c], d1 = w_dw3[CIN + c], d2 = w_dw3[2*CIN + c];
        const float bd = b_dw3[c];
        auto ci3 = [&](int t) -> float {
          if (t < 0) return -38.0f;           // quantize(0) with s=4.459,o=38
          return (float)c3r[((t + 112) % 56)*CIN + c];
        };
        for (int j = 0; j < PF; ++j) {
          const int t = pt0 + j;
          Tb[c*PF + j] = fmaf(d0, ci3(t-18), fmaf(d1, ci3(t-9), fmaf(d2, ci3(t), bd)));
        }
      }
      __syncthreads();

      // -------------- stage 8: pw3 GEMV -> leaky -> Tb -----------------------
      gemv(w_pw3, Tb, oc4, fb0, acc);
      {
        const float4 b4 = *(const float4*)&b_pw3[oc4];
        const float bb[4] = {b4.x, b4.y, b4.z, b4.w};
#pragma unroll
        for (int a = 0; a < 4; ++a)
#pragma unroll
          for (int b = 0; b < 8; ++b) acc[a][b] = lrelu(acc[a][b] + bb[a]);
      }
      __syncthreads();
#pragma unroll
      for (int a = 0; a < 4; ++a) {
        *(float4*)&Tb[(oc4 + a)*PF + fb0]     = make_float4(acc[a][0],acc[a][1],acc[a][2],acc[a][3]);
        *(float4*)&Tb[(oc4 + a)*PF + fb0 + 4] = make_float4(acc[a][4],acc[a][5],acc[a][6],acc[a][7]);
      }
      __syncthreads();

      // -------------- stage 9: lc3 GEMV -> +r3 -> final dequant -> out -------
      gemv(w_lc3, Tb, oc4, fb0, acc);
      {
        const float4 b4 = *(const float4*)&b_lc3[oc4];
        const float bb[4] = {b4.x, b4.y, b4.z, b4.w};
#pragma unroll
        for (int b = 0; b < 8; ++b) {
          const int t = pt0 + fb0 + b;
          if (t < LOUT) {
            float o[4];
#pragma unroll
            for (int a = 0; a < 4; ++a) {
              const float r4 = (acc[a][b] + bb[a]) + resf[a][b];
              o[a] = (lrelu(r4) + 34.0f) * 3.698859930038452f;
            }
            *(float4*)&out[t*CIN + oc4] = make_float4(o[0], o[1], o[2], o[3]);
          }
        }
      }
    }
  }
}

extern "C" void kernel_launch(void* const* d_in, const int* in_sizes, int n_in,
                              void* d_out, int out_size, void* d_ws, size_t ws_size,
                              hipStream_t stream) {
  (void)in_sizes; (void)n_in; (void)d_ws; (void)ws_size; (void)out_size;
  const float* x       = (const float*)d_in[0];
  // d_in[1..4]: first/res1/res2/res3 buffers — all zeros, padding handled inline
  const float* w_first = (const float*)d_in[5];
  const float* b_first = (const float*)d_in[6];
  const float* w_dw1   = (const float*)d_in[7];
  const float* b_dw1   = (const float*)d_in[8];
  const float* w_pw1   = (const float*)d_in[9];
  const float* b_pw1   = (const float*)d_in[10];
  const float* w_lc1   = (const float*)d_in[11];
  const float* b_lc1   = (const float*)d_in[12];
  const float* w_dw2   = (const float*)d_in[13];
  const float* b_dw2   = (const float*)d_in[14];
  const float* w_pw2   = (const float*)d_in[15];
  const float* b_pw2   = (const float*)d_in[16];
  const float* w_lc2   = (const float*)d_in[17];
  const float* b_lc2   = (const float*)d_in[18];
  const float* w_dw3   = (const float*)d_in[19];
  const float* b_dw3   = (const float*)d_in[20];
  const float* w_pw3   = (const float*)d_in[21];
  const float* b_pw3   = (const float*)d_in[22];
  const float* w_lc3   = (const float*)d_in[23];
  const float* b_lc3   = (const float*)d_in[24];

  enc_kernel<<<dim3(NBLK), dim3(256), 0, stream>>>(
      x, w_first, b_first,
      w_dw1, b_dw1, w_pw1, b_pw1, w_lc1, b_lc1,
      w_dw2, b_dw2, w_pw2, b_pw2, w_lc2, b_lc2,
      w_dw3, b_dw3, w_pw3, b_pw3, w_lc3, b_lc3,
      (float*)d_out);
}

// Round 2
// 1395.513 us; speedup vs baseline: 1.4390x; 1.4390x over previous
//
#include <hip/hip_runtime.h>

// Fully fused quantized encoder, MFMA edition.
// GEMMs: D[oc][frame] = W^T · act, bf16 hi/lo split (3 MFMAs, al*bl dropped ~2^-18).
// Weights pre-packed into d_ws in MFMA A-frag stream order (pack_w kernel).
// Activations live in LDS in MFMA B-frag stream order (hi 16KB + lo 16KB).
// Depthwise / first-conv stages are scalar per-channel with frame-rotation to
// spread LDS bank writes. r2 / ci3 int8 history rings as before (exact).

#define CIN   256
#define LOUT  120000
#define TIN   600000
#define PF    32
#define FB    128
#define NBLK  ((LOUT + FB - 1) / FB)   // 938

typedef float fx4 __attribute__((ext_vector_type(4)));
typedef short bx8 __attribute__((ext_vector_type(8)));

// ---- LDS map ----
#define BF_OFF   0        // 32768 B: B-frags (32 frames x 256 k), hi + lo bf16
#define CI1_OFF  32768    // 17408 B: ci1 bf16 [c][34]
#define R2R_OFF  50176    //  9880 B: r2 ring, 38 slots x 260 B (stride 260 = bank spread)
#define C3R_OFF  60056    // 13000 B: c3 ring, 50 slots x 260 B
#define XW_OFF   73056    //   704 B: x window (176 floats)
#define LDS_SZ   73760

__device__ __forceinline__ float lrelu(float v){ return v >= 0.0f ? v : 0.3f*v; }
__device__ __forceinline__ float clip8(float v){ return fminf(fmaxf(v, -128.0f), 127.0f); }
__device__ __forceinline__ unsigned short f2bf(float f){
  unsigned u = __builtin_bit_cast(unsigned, f);
  return (unsigned short)((u + 0x7FFFu + ((u >> 16) & 1u)) >> 16);  // RNE
}
__device__ __forceinline__ float bf2f(unsigned short h){
  unsigned u = ((unsigned)h) << 16;
  return __builtin_bit_cast(float, u);
}

// GEMM: acc[mt][nt] += Wmat-tile x B-act-tile, 3-term hi/lo split.
// Aw: per-wave weight base (global, frag-stream). Bf: LDS B-frag base.
__device__ __forceinline__ void gemm_mfma(const char* __restrict__ Aw,
                                          const char* __restrict__ Bf,
                                          int lofs, fx4 acc[4][2])
{
#pragma unroll 2
  for (int kk = 0; kk < 8; ++kk) {
    bx8 Bh0 = *(const bx8*)(Bf + kk*4096 +        lofs);
    bx8 Bl0 = *(const bx8*)(Bf + kk*4096 + 1024 + lofs);
    bx8 Bh1 = *(const bx8*)(Bf + kk*4096 + 2048 + lofs);
    bx8 Bl1 = *(const bx8*)(Bf + kk*4096 + 3072 + lofs);
#pragma unroll
    for (int mt = 0; mt < 4; ++mt) {
      bx8 Ah = *(const bx8*)(Aw + (mt*8 + kk)*2048 +        lofs);
      bx8 Al = *(const bx8*)(Aw + (mt*8 + kk)*2048 + 1024 + lofs);
      acc[mt][0] = __builtin_amdgcn_mfma_f32_16x16x32_bf16(Ah, Bh0, acc[mt][0], 0, 0, 0);
      acc[mt][0] = __builtin_amdgcn_mfma_f32_16x16x32_bf16(Al, Bh0, acc[mt][0], 0, 0, 0);
      acc[mt][0] = __builtin_amdgcn_mfma_f32_16x16x32_bf16(Ah, Bl0, acc[mt][0], 0, 0, 0);
      acc[mt][1] = __builtin_amdgcn_mfma_f32_16x16x32_bf16(Ah, Bh1, acc[mt][1], 0, 0, 0);
      acc[mt][1] = __builtin_amdgcn_mfma_f32_16x16x32_bf16(Al, Bh1, acc[mt][1], 0, 0, 0);
      acc[mt][1] = __builtin_amdgcn_mfma_f32_16x16x32_bf16(Ah, Bl1, acc[mt][1], 0, 0, 0);
    }
  }
}

// Pack 6 weight matrices [ic][oc] into A-frag stream (hi+lo bf16) in d_ws.
// A[m=oc][k=ic]; frag for (mat, wm=oc>>4, kk=ic>>5, hl, lane(q=k-quad, n=oc&15)).
__global__ void pack_w(const float* __restrict__ w0, const float* __restrict__ w1,
                       const float* __restrict__ w2, const float* __restrict__ w3,
                       const float* __restrict__ w4, const float* __restrict__ w5,
                       char* __restrict__ Apk)
{
  const int l = blockIdx.x*256 + threadIdx.x;          // < 49152
  const int lane = l & 63, kk = (l >> 6) & 7, wm = (l >> 9) & 15, mat = l >> 13;
  const float* W = mat==0?w0 : mat==1?w1 : mat==2?w2 : mat==3?w3 : mat==4?w4 : w5;
  const int oc = wm*16 + (lane & 15);
  const int k0 = kk*32 + (lane >> 4)*8;
  unsigned short h[8], lo[8];
#pragma unroll
  for (int j = 0; j < 8; ++j) {
    const float v = W[(k0 + j)*CIN + oc];
    h[j]  = f2bf(v);
    lo[j] = f2bf(v - bf2f(h[j]));
  }
  char* base = Apk + mat*262144 + (wm*8 + kk)*2048 + lane*16;
  *(ushort4*)(base)        = make_ushort4(h[0],  h[1],  h[2],  h[3]);
  *(ushort4*)(base + 8)    = make_ushort4(h[4],  h[5],  h[6],  h[7]);
  *(ushort4*)(base + 1024) = make_ushort4(lo[0], lo[1], lo[2], lo[3]);
  *(ushort4*)(base + 1032) = make_ushort4(lo[4], lo[5], lo[6], lo[7]);
}

__launch_bounds__(256, 2)
__global__ void enc_kernel(const float* __restrict__ x,
                           const char* __restrict__ Apk,
                           const float* __restrict__ w_first, const float* __restrict__ b_first,
                           const float* __restrict__ w_dw1, const float* __restrict__ b_dw1,
                           const float* __restrict__ b_pw1, const float* __restrict__ b_lc1,
                           const float* __restrict__ w_dw2, const float* __restrict__ b_dw2,
                           const float* __restrict__ b_pw2, const float* __restrict__ b_lc2,
                           const float* __restrict__ w_dw3, const float* __restrict__ b_dw3,
                           const float* __restrict__ b_pw3, const float* __restrict__ b_lc3,
                           float* __restrict__ out)
{
  __shared__ __align__(16) char lds[LDS_SZ];
  const int tid  = threadIdx.x;
  const int lane = tid & 63;
  const int wv   = tid >> 6;
  const int qq   = lane >> 4;
  const int nn   = lane & 15;
  const int lofs = lane * 16;
  const int t0   = blockIdx.x * FB;
  const fx4 fz = {0.0f, 0.0f, 0.0f, 0.0f};

  // hoisted per-channel weights (c = tid)
  float wf[10];
#pragma unroll
  for (int k = 0; k < 10; ++k) wf[k] = w_first[k*CIN + tid];
  const float bfv = b_first[tid];
  const float d10 = w_dw1[tid], d11 = w_dw1[CIN+tid], d12 = w_dw1[2*CIN+tid], bd1 = b_dw1[tid];
  const float d20 = w_dw2[tid], d21 = w_dw2[CIN+tid], d22 = w_dw2[2*CIN+tid], bd2 = b_dw2[tid];
  const float d30 = w_dw3[tid], d31 = w_dw3[CIN+tid], d32 = w_dw3[2*CIN+tid], bd3 = b_dw3[tid];

  // frag-write constants for channel c = tid (k-dim position)
  const int wofs_c = (tid >> 5)*4096 + (((tid & 31) >> 3)*16)*16 + (tid & 7)*2;

  int c0m[4];
#pragma unroll
  for (int mt = 0; mt < 4; ++mt) c0m[mt] = wv*64 + mt*16 + qq*4;

  float resf[4][2][4];
  fx4 acc[4][2];

  for (int pass = 0; pass < 5; ++pass) {
    const int pt0 = t0 - 32 + pass*32;
    const int xbase = 5*pt0 - 15;

    __syncthreads();                       // prev-pass B/ci1/xw readers done
    if (tid < 176) {
      const int gx = xbase + tid;
      *(float*)&lds[XW_OFF + tid*4] = (gx >= 0 && gx < TIN) ? x[gx] : 0.0f;
    }
    __syncthreads();

    // ---- S1: first conv + leaky -> ci1 (bf16), j=0..33 <-> frame pt0+j-2 ----
    for (int j = 0; j < 34; ++j) {
      const int t = pt0 + j - 2;
      float a = 0.0f;
#pragma unroll
      for (int k = 0; k < 10; ++k)
        a = fmaf(*(const float*)&lds[XW_OFF + (5*j + k)*4], wf[k], a);
      const float ci = (t < 0) ? 0.0f : lrelu(a + bfv);
      *(unsigned short*)&lds[CI1_OFF + (tid*34 + j)*2] = f2bf(ci);
    }
    __syncthreads();

    // ---- S1b: dw1 (dil 1) -> B-frags (rotated frames for bank spread) ----
    for (int s = 0; s < 32; ++s) {
      const int jr = (s + tid) & 31;
      const float c2 = bf2f(*(const unsigned short*)&lds[CI1_OFF + (tid*34 + jr    )*2]);
      const float c1 = bf2f(*(const unsigned short*)&lds[CI1_OFF + (tid*34 + jr + 1)*2]);
      const float c0 = bf2f(*(const unsigned short*)&lds[CI1_OFF + (tid*34 + jr + 2)*2]);
      const float v = fmaf(d10, c2, fmaf(d11, c1, fmaf(d12, c0, bd1)));
      const int ab = wofs_c + ((jr >> 4)*2048) + ((jr & 15)*16);
      const unsigned short hi = f2bf(v);
      *(unsigned short*)&lds[BF_OFF + ab]        = hi;
      *(unsigned short*)&lds[BF_OFF + ab + 1024] = f2bf(v - bf2f(hi));
    }
    __syncthreads();

    // ---- G2: pw1 ----
#pragma unroll
    for (int mt = 0; mt < 4; ++mt) { acc[mt][0] = fz; acc[mt][1] = fz; }
    gemm_mfma(Apk + 0*262144 + wv*65536, (const char*)lds + BF_OFF, lofs, acc);
    __syncthreads();
    // E2: +bias, quantize(17.63,-67), leaky -> B-frags
#pragma unroll
    for (int mt = 0; mt < 4; ++mt) {
      const int c0 = c0m[mt];
      const float4 bb = *(const float4*)&b_pw1[c0];
      const float bbv[4] = {bb.x, bb.y, bb.z, bb.w};
      const int ab0 = (c0 >> 5)*4096 + (((c0 & 31) >> 3)*16 + nn)*16 + (c0 & 7)*2;
#pragma unroll
      for (int nt = 0; nt < 2; ++nt) {
        unsigned short h4[4], l4[4];
#pragma unroll
        for (int r = 0; r < 4; ++r) {
          const float h  = acc[mt][nt][r] + bbv[r];
          const float qv = clip8(rintf(h / 17.62967872619629f + 67.0f));
          const float av = lrelu(qv);
          h4[r] = f2bf(av);
          l4[r] = f2bf(av - bf2f(h4[r]));
        }
        const int ab = ab0 + nt*2048;
        *(ushort4*)&lds[BF_OFF + ab]        = make_ushort4(h4[0], h4[1], h4[2], h4[3]);
        *(ushort4*)&lds[BF_OFF + ab + 1024] = make_ushort4(l4[0], l4[1], l4[2], l4[3]);
      }
    }
    __syncthreads();

    // ---- G3: lc1 ----
#pragma unroll
    for (int mt = 0; mt < 4; ++mt) { acc[mt][0] = fz; acc[mt][1] = fz; }
    gemm_mfma(Apk + 1*262144 + wv*65536, (const char*)lds + BF_OFF, lofs, acc);
    __syncthreads();
    // E3: ro1 dequant + r1(recompute) + b_first -> quantize(12.72,-23) -> resf + r2 ring
#pragma unroll
    for (int nt = 0; nt < 2; ++nt) {
      const int f = nt*16 + nn;
      const int t = pt0 + f;
      float xv[10];
#pragma unroll
      for (int k = 0; k < 10; ++k) xv[k] = *(const float*)&lds[XW_OFF + (5*f + 10 + k)*4];
      const int slot = (t + 3800) % 38;
#pragma unroll
      for (int mt = 0; mt < 4; ++mt) {
        const int c0 = c0m[mt];
        float r1v[4] = {0.0f, 0.0f, 0.0f, 0.0f};
#pragma unroll
        for (int k = 0; k < 10; ++k) {
          const float4 wk = *(const float4*)&w_first[k*CIN + c0];
          r1v[0] = fmaf(xv[k], wk.x, r1v[0]);
          r1v[1] = fmaf(xv[k], wk.y, r1v[1]);
          r1v[2] = fmaf(xv[k], wk.z, r1v[2]);
          r1v[3] = fmaf(xv[k], wk.w, r1v[3]);
        }
        const float4 bl = *(const float4*)&b_lc1[c0];
        const float4 bf = *(const float4*)&b_first[c0];
        const float blv[4]  = {bl.x, bl.y, bl.z, bl.w};
        const float bfa[4]  = {bf.x, bf.y, bf.z, bf.w};
        int pk = 0;
#pragma unroll
        for (int r = 0; r < 4; ++r) {
          const float ro1 = (acc[mt][nt][r] + blv[r] - 16.0f) * 6.528060436248779f;
          const float v   = (r1v[r] + bfa[r]) + ro1;
          const float q   = clip8(rintf(v / 12.716455459594727f + 23.0f));
          resf[mt][nt][r] = q;
          pk |= ((int)q & 255) << (8*r);
        }
        *(int*)&lds[R2R_OFF + slot*260 + c0] = pk;
      }
    }
    __syncthreads();

    // ---- S4: dw2 (dil 3) from r2 ring -> B-frags ----
    for (int s = 0; s < 32; ++s) {
      const int jr = (s + tid) & 31;
      const int t = pt0 + jr;
      float cv[3];
#pragma unroll
      for (int li = 0; li < 3; ++li) {
        const int tt = t - 3*(2 - li);          // lags 6, 3, 0
        float c;
        if (tt < 0) c = -47.0f;
        else {
          const int sl = (tt + 3800) % 38;
          const float r = (float)*(const signed char*)&lds[R2R_OFF + sl*260 + tid];
          const float dq = (lrelu(r) + 47.0f) * 5.548006534576416f;
          c = clip8(rintf(dq / 5.548006534576416f - 47.0f));
        }
        cv[li] = c;
      }
      const float v = fmaf(d20, cv[0], fmaf(d21, cv[1], fmaf(d22, cv[2], bd2)));
      const int ab = wofs_c + ((jr >> 4)*2048) + ((jr & 15)*16);
      const unsigned short hi = f2bf(v);
      *(unsigned short*)&lds[BF_OFF + ab]        = hi;
      *(unsigned short*)&lds[BF_OFF + ab + 1024] = f2bf(v - bf2f(hi));
    }
    __syncthreads();

    // ---- G5: pw2 ----
#pragma unroll
    for (int mt = 0; mt < 4; ++mt) { acc[mt][0] = fz; acc[mt][1] = fz; }
    gemm_mfma(Apk + 2*262144 + wv*65536, (const char*)lds + BF_OFF, lofs, acc);
    __syncthreads();
    // E5: +bias, leaky -> B-frags
#pragma unroll
    for (int mt = 0; mt < 4; ++mt) {
      const int c0 = c0m[mt];
      const float4 bb = *(const float4*)&b_pw2[c0];
      const float bbv[4] = {bb.x, bb.y, bb.z, bb.w};
      const int ab0 = (c0 >> 5)*4096 + (((c0 & 31) >> 3)*16 + nn)*16 + (c0 & 7)*2;
#pragma unroll
      for (int nt = 0; nt < 2; ++nt) {
        unsigned short h4[4], l4[4];
#pragma unroll
        for (int r = 0; r < 4; ++r) {
          const float av = lrelu(acc[mt][nt][r] + bbv[r]);
          h4[r] = f2bf(av);
          l4[r] = f2bf(av - bf2f(h4[r]));
        }
        const int ab = ab0 + nt*2048;
        *(ushort4*)&lds[BF_OFF + ab]        = make_ushort4(h4[0], h4[1], h4[2], h4[3]);
        *(ushort4*)&lds[BF_OFF + ab + 1024] = make_ushort4(l4[0], l4[1], l4[2], l4[3]);
      }
    }
    __syncthreads();

    // ---- G6: lc2 ----
#pragma unroll
    for (int mt = 0; mt < 4; ++mt) { acc[mt][0] = fz; acc[mt][1] = fz; }
    gemm_mfma(Apk + 3*262144 + wv*65536, (const char*)lds + BF_OFF, lofs, acc);
    __syncthreads();
    // E6: r3 = ro2 + r2 -> resf; ci3 quant -> c3 ring
#pragma unroll
    for (int nt = 0; nt < 2; ++nt) {
      const int t = pt0 + nt*16 + nn;
      const int slot = (t + 5000) % 50;
#pragma unroll
      for (int mt = 0; mt < 4; ++mt) {
        const int c0 = c0m[mt];
        const float4 bl = *(const float4*)&b_lc2[c0];
        const float blv[4] = {bl.x, bl.y, bl.z, bl.w};
        int pk = 0;
#pragma unroll
        for (int r = 0; r < 4; ++r) {
          const float r3 = (acc[mt][nt][r] + blv[r]) + resf[mt][nt][r];
          resf[mt][nt][r] = r3;
          const float dq = (lrelu(r3) + 38.0f) * 4.458680152893066f;
          const float q  = clip8(rintf(dq / 4.458680152893066f - 38.0f));
          pk |= ((int)q & 255) << (8*r);
        }
        *(int*)&lds[C3R_OFF + slot*260 + c0] = pk;
      }
    }
    __syncthreads();

    if (pass == 0) continue;

    // ---- S7: dw3 (dil 9) from c3 ring -> B-frags ----
    for (int s = 0; s < 32; ++s) {
      const int jr = (s + tid) & 31;
      const int t = pt0 + jr;
      float cv[3];
#pragma unroll
      for (int li = 0; li < 3; ++li) {
        const int tt = t - 9*(2 - li);          // lags 18, 9, 0
        float c;
        if (tt < 0) c = -38.0f;
        else {
          const int sl = (tt + 5000) % 50;
          c = (float)*(const signed char*)&lds[C3R_OFF + sl*260 + tid];
        }
        cv[li] = c;
      }
      const float v = fmaf(d30, cv[0], fmaf(d31, cv[1], fmaf(d32, cv[2], bd3)));
      const int ab = wofs_c + ((jr >> 4)*2048) + ((jr & 15)*16);
      const unsigned short hi = f2bf(v);
      *(unsigned short*)&lds[BF_OFF + ab]        = hi;
      *(unsigned short*)&lds[BF_OFF + ab + 1024] = f2bf(v - bf2f(hi));
    }
    __syncthreads();

    // ---- G8: pw3 ----
#pragma unroll
    for (int mt = 0; mt < 4; ++mt) { acc[mt][0] = fz; acc[mt][1] = fz; }
    gemm_mfma(Apk + 4*262144 + wv*65536, (const char*)lds + BF_OFF, lofs, acc);
    __syncthreads();
    // E8: +bias, leaky -> B-frags
#pragma unroll
    for (int mt = 0; mt < 4; ++mt) {
      const int c0 = c0m[mt];
      const float4 bb = *(const float4*)&b_pw3[c0];
      const float bbv[4] = {bb.x, bb.y, bb.z, bb.w};
      const int ab0 = (c0 >> 5)*4096 + (((c0 & 31) >> 3)*16 + nn)*16 + (c0 & 7)*2;
#pragma unroll
      for (int nt = 0; nt < 2; ++nt) {
        unsigned short h4[4], l4[4];
#pragma unroll
        for (int r = 0; r < 4; ++r) {
          const float av = lrelu(acc[mt][nt][r] + bbv[r]);
          h4[r] = f2bf(av);
          l4[r] = f2bf(av - bf2f(h4[r]));
        }
        const int ab = ab0 + nt*2048;
        *(ushort4*)&lds[BF_OFF + ab]        = make_ushort4(h4[0], h4[1], h4[2], h4[3]);
        *(ushort4*)&lds[BF_OFF + ab + 1024] = make_ushort4(l4[0], l4[1], l4[2], l4[3]);
      }
    }
    __syncthreads();

    // ---- G9: lc3 + final epilogue -> out ----
#pragma unroll
    for (int mt = 0; mt < 4; ++mt) { acc[mt][0] = fz; acc[mt][1] = fz; }
    gemm_mfma(Apk + 5*262144 + wv*65536, (const char*)lds + BF_OFF, lofs, acc);
#pragma unroll
    for (int nt = 0; nt < 2; ++nt) {
      const int t = pt0 + nt*16 + nn;
      if (t < LOUT) {
#pragma unroll
        for (int mt = 0; mt < 4; ++mt) {
          const int c0 = c0m[mt];
          const float4 bl = *(const float4*)&b_lc3[c0];
          const float blv[4] = {bl.x, bl.y, bl.z, bl.w};
          float o[4];
#pragma unroll
          for (int r = 0; r < 4; ++r) {
            const float r4 = (acc[mt][nt][r] + blv[r]) + resf[mt][nt][r];
            o[r] = (lrelu(r4) + 34.0f) * 3.698859930038452f;
          }
          *(float4*)&out[t*CIN + c0] = make_float4(o[0], o[1], o[2], o[3]);
        }
      }
    }
  }
}

extern "C" void kernel_launch(void* const* d_in, const int* in_sizes, int n_in,
                              void* d_out, int out_size, void* d_ws, size_t ws_size,
                              hipStream_t stream) {
  (void)in_sizes; (void)n_in; (void)out_size; (void)ws_size;
  const float* x       = (const float*)d_in[0];
  const float* w_first = (const float*)d_in[5];
  const float* b_first = (const float*)d_in[6];
  const float* w_dw1   = (const float*)d_in[7];
  const float* b_dw1   = (const float*)d_in[8];
  const float* w_pw1   = (const float*)d_in[9];
  const float* b_pw1   = (const float*)d_in[10];
  const float* w_lc1   = (const float*)d_in[11];
  const float* b_lc1   = (const float*)d_in[12];
  const float* w_dw2   = (const float*)d_in[13];
  const float* b_dw2   = (const float*)d_in[14];
  const float* w_pw2   = (const float*)d_in[15];
  const float* b_pw2   = (const float*)d_in[16];
  const float* w_lc2   = (const float*)d_in[17];
  const float* b_lc2   = (const float*)d_in[18];
  const float* w_dw3   = (const float*)d_in[19];
  const float* b_dw3   = (const float*)d_in[20];
  const float* w_pw3   = (const float*)d_in[21];
  const float* b_pw3   = (const float*)d_in[22];
  const float* w_lc3   = (const float*)d_in[23];
  const float* b_lc3   = (const float*)d_in[24];

  char* Apk = (char*)d_ws;                       // 6 x 262144 B = 1.5 MB

  pack_w<<<dim3(192), dim3(256), 0, stream>>>(w_pw1, w_lc1, w_pw2, w_lc2, w_pw3, w_lc3, Apk);
  enc_kernel<<<dim3(NBLK), dim3(256), 0, stream>>>(
      x, Apk, w_first, b_first,
      w_dw1, b_dw1, b_pw1, b_lc1,
      w_dw2, b_dw2, b_pw2, b_lc2,
      w_dw3, b_dw3, b_pw3, b_lc3,
      (float*)d_out);
}